// Round 4
// baseline (2944.756 us; speedup 1.0000x reference)
//
#include <hip/hip_runtime.h>

#define FDIM 128
#define HDIM 32
#define BN_EPS 1e-5f
#define BK 64          // destination nodes per bucket
#define CHUNK 16384    // edges per partition/hist block
#define BMAX 4096      // max buckets supported (N <= 262144)

// ---------- fused per-node degree + per-bucket histogram ----------
__global__ void k_hist2(const int* __restrict__ col, int* __restrict__ counts,
                        int* __restrict__ bcounts, int E, int B) {
    __shared__ int h[BMAX];
    for (int i = threadIdx.x; i < B; i += 256) h[i] = 0;
    __syncthreads();
    int base = blockIdx.x * CHUNK;
    int end = min(base + CHUNK, E);
    for (int e = base + threadIdx.x; e < end; e += 256) {
        int c = col[e];
        atomicAdd(&counts[c], 1);   // per-node in-degree (for dinv)
        atomicAdd(&h[c >> 6], 1);   // per-bucket (LDS)
    }
    __syncthreads();
    for (int i = threadIdx.x; i < B; i += 256)
        if (h[i]) atomicAdd(&bcounts[i], h[i]);
}

__global__ void k_dinv(const int* __restrict__ counts, float* __restrict__ dinv, int n) {
    int i = blockIdx.x * 256 + threadIdx.x;
    if (i < n) dinv[i] = rsqrtf((float)(counts[i] + 1));  // +1 self-loop
}

// ---------- single-block exclusive scan of bucket counts ----------
__global__ void k_bscan(const int* __restrict__ bcounts, int* __restrict__ boff,
                        int* __restrict__ bcur, int B, int E) {
    __shared__ int tsum[256];
    __shared__ int wtot[4];
    const int t = threadIdx.x;
    const int per = (B + 255) / 256;
    const int b0 = t * per;
    int s = 0;
    for (int k = 0; k < per; ++k) { int i = b0 + k; if (i < B) s += bcounts[i]; }
    tsum[t] = s;
    __syncthreads();
    int lane = t & 63, w = t >> 6;
    int v = tsum[t];
    int inc = v;
    for (int off = 1; off < 64; off <<= 1) {
        int u = __shfl_up(inc, off);
        if (lane >= off) inc += u;
    }
    if (lane == 63) wtot[w] = inc;
    __syncthreads();
    int pre = 0;
    for (int k = 0; k < w; ++k) pre += wtot[k];
    int acc = pre + inc - v;  // exclusive prefix
    for (int k = 0; k < per; ++k) {
        int i = b0 + k;
        if (i < B) { boff[i] = acc; bcur[i] = acc; acc += bcounts[i]; }
    }
    if (t == 0) boff[B] = E;
}

// ---------- partition: pairs[] grouped by dst bucket, packed (src<<6 | dst&63) ----------
__global__ void k_partition(const int* __restrict__ row, const int* __restrict__ col,
                            int* __restrict__ bcur, unsigned* __restrict__ pairs,
                            int E, int B) {
    __shared__ int h[BMAX];
    for (int i = threadIdx.x; i < B; i += 256) h[i] = 0;
    __syncthreads();
    int base = blockIdx.x * CHUNK;
    int end = min(base + CHUNK, E);
    for (int e = base + threadIdx.x; e < end; e += 256)
        atomicAdd(&h[col[e] >> 6], 1);
    __syncthreads();
    for (int i = threadIdx.x; i < B; i += 256) {
        int c = h[i];
        if (c) h[i] = atomicAdd(&bcur[i], c);  // reserve contiguous range; h = running cursor
    }
    __syncthreads();
    for (int e = base + threadIdx.x; e < end; e += 256) {
        int c = col[e], r = row[e];
        int pos = atomicAdd(&h[c >> 6], 1);
        pairs[pos] = ((unsigned)r << 6) | (unsigned)(c & 63);
    }
}

// ---------- GEMM: Y[n,32] = dinv[n] * (X[n,K] @ W[K,32]); optional fused BN+ReLU on X ----------
template <int K, bool APPLY_BN>
__global__ void k_gemm(const float* __restrict__ X, const float* __restrict__ W,
                       const float* __restrict__ dinv, float* __restrict__ Y, int n,
                       const float* __restrict__ stats, const float* __restrict__ gamma,
                       const float* __restrict__ beta, float invN) {
    __shared__ __align__(16) float Ws[K * HDIM];
    __shared__ __align__(16) float Xs[8 * K];
    __shared__ float bnsc[K], bnsh[K];
    const int tid = threadIdx.x;
    const int row0 = blockIdx.x * 8;

    if (APPLY_BN) {
        if (tid < K) {
            float mean = stats[tid] * invN;
            float var = stats[K + tid] * invN - mean * mean;
            float sc = gamma[tid] * rsqrtf(var + BN_EPS);
            bnsc[tid] = sc;
            bnsh[tid] = beta[tid] - mean * sc;
        }
        __syncthreads();
    }
    for (int i = tid * 4; i < K * HDIM; i += 1024) {
        *(float4*)&Ws[i] = *(const float4*)&W[i];
    }
    for (int i = tid * 4; i < 8 * K; i += 1024) {
        int r = i / K, k = i % K;
        int gr = row0 + r;
        float4 v = make_float4(0.f, 0.f, 0.f, 0.f);
        if (gr < n) v = *(const float4*)&X[(size_t)gr * K + k];
        if (APPLY_BN) {
            v.x = fmaxf(v.x * bnsc[k]     + bnsh[k],     0.f);
            v.y = fmaxf(v.y * bnsc[k + 1] + bnsh[k + 1], 0.f);
            v.z = fmaxf(v.z * bnsc[k + 2] + bnsh[k + 2], 0.f);
            v.w = fmaxf(v.w * bnsc[k + 3] + bnsh[k + 3], 0.f);
        }
        *(float4*)&Xs[i] = v;
    }
    __syncthreads();
    const int r = tid >> 5, c = tid & 31;
    const int grow = row0 + r;
    if (grow < n) {
        float acc = 0.f;
#pragma unroll
        for (int k = 0; k < K; ++k) acc += Xs[r * K + k] * Ws[k * HDIM + c];
        Y[(size_t)grow * HDIM + c] = dinv[grow] * acc;
    }
}

// ---------- bucketed aggregate with LDS-atomic tile; fused self-loop+bias+BN-stats ----------
__global__ __launch_bounds__(256) void k_agg(const float* __restrict__ hp,
                                             const float* __restrict__ dinv,
                                             const int* __restrict__ boff,
                                             const unsigned* __restrict__ pairs,
                                             const float* __restrict__ bias,
                                             float* __restrict__ agg,
                                             float* __restrict__ stats, int N, int B) {
    __shared__ float tile[BK][HDIM];
    __shared__ float ls[256], ls2[256];
    const int t = threadIdx.x;
    const int j = t & 31;
    const int sub = t >> 5;  // 0..7
    const float bj = bias[j];
    float s = 0.f, s2 = 0.f;

    for (int bb = blockIdx.x; bb < B; bb += gridDim.x) {
        for (int i = t; i < BK * HDIM; i += 256) ((float*)tile)[i] = 0.f;
        __syncthreads();
        const int beg = boff[bb], end = boff[bb + 1];
        int e = beg + sub;
        for (; e + 24 < end; e += 32) {
            unsigned p0 = pairs[e], p1 = pairs[e + 8], p2 = pairs[e + 16], p3 = pairs[e + 24];
            float v0 = hp[(size_t)(p0 >> 6) * HDIM + j];
            float v1 = hp[(size_t)(p1 >> 6) * HDIM + j];
            float v2 = hp[(size_t)(p2 >> 6) * HDIM + j];
            float v3 = hp[(size_t)(p3 >> 6) * HDIM + j];
            atomicAdd(&tile[p0 & 63][j], v0);
            atomicAdd(&tile[p1 & 63][j], v1);
            atomicAdd(&tile[p2 & 63][j], v2);
            atomicAdd(&tile[p3 & 63][j], v3);
        }
        for (; e < end; e += 8) {
            unsigned p = pairs[e];
            atomicAdd(&tile[p & 63][j], hp[(size_t)(p >> 6) * HDIM + j]);
        }
        __syncthreads();
        const int n0 = bb * BK;
        for (int i = t; i < BK * HDIM; i += 256) {
            int loc = i >> 5;           // j = i & 31 == t & 31 (256 % 32 == 0)
            int n = n0 + loc;
            if (n < N) {
                float out = dinv[n] * (tile[loc][j] + hp[(size_t)n * HDIM + j]) + bj;
                agg[(size_t)n * HDIM + j] = out;
                s += out;
                s2 += out * out;
            }
        }
        __syncthreads();  // epilogue reads done before next bucket's zeroing
    }

    ls[t] = s;
    ls2[t] = s2;
    __syncthreads();
    if (t < 32) {
        float a = 0.f;
        for (int k = t; k < 256; k += 32) a += ls[k];
        atomicAdd(&stats[t], a);
    } else if (t < 64) {
        int jj = t - 32;
        float a = 0.f;
        for (int k = jj; k < 256; k += 32) a += ls2[k];
        atomicAdd(&stats[HDIM + jj], a);
    }
}

// ---------- final batchnorm apply (layer 2, no relu) ----------
__global__ void k_bnapply(const float* __restrict__ a, const float* __restrict__ stats,
                          const float* __restrict__ gamma, const float* __restrict__ beta,
                          float* __restrict__ out, int n, float invN) {
    int i = blockIdx.x * 256 + threadIdx.x;
    if (i < n * HDIM) {
        int j = i & 31;
        float mean = stats[j] * invN;
        float var = stats[HDIM + j] * invN - mean * mean;
        float g = gamma[j] * rsqrtf(var + BN_EPS);
        out[i] = (a[i] - mean) * g + beta[j];
    }
}

extern "C" void kernel_launch(void* const* d_in, const int* in_sizes, int n_in,
                              void* d_out, int out_size, void* d_ws, size_t ws_size,
                              hipStream_t stream) {
    const float* x   = (const float*)d_in[0];
    const int*   ei  = (const int*)d_in[1];
    const float* W1  = (const float*)d_in[2];
    const float* b1  = (const float*)d_in[3];
    const float* g1  = (const float*)d_in[4];
    const float* be1 = (const float*)d_in[5];
    const float* W2  = (const float*)d_in[6];
    const float* b2  = (const float*)d_in[7];
    const float* g2  = (const float*)d_in[8];
    const float* be2 = (const float*)d_in[9];

    const int N = in_sizes[0] / FDIM;
    const int E = in_sizes[1] / 2;
    const int* row = ei;      // source
    const int* col = ei + E;  // target
    const int B = (N + BK - 1) / BK;   // buckets (1563 for N=100k, fits BMAX)

    char* p = (char*)d_ws;
    auto alloc = [&](size_t bytes) { char* r = p; p += (bytes + 255) & ~(size_t)255; return r; };
    int*      counts  = (int*)alloc((size_t)N * 4);
    float*    dinv    = (float*)alloc((size_t)N * 4);
    int*      bcounts = (int*)alloc((size_t)B * 4);
    int*      boff    = (int*)alloc((size_t)(B + 1) * 4);
    int*      bcur    = (int*)alloc((size_t)B * 4);
    unsigned* pairs   = (unsigned*)alloc((size_t)E * 4);
    float*    B1      = (float*)alloc((size_t)N * HDIM * 4);
    float*    B2      = (float*)alloc((size_t)N * HDIM * 4);
    float*    stats   = (float*)alloc(512);  // layer1 [0,64), layer2 [64,128)

    const float invN = 1.0f / (float)N;
    const int EB = (E + CHUNK - 1) / CHUNK;

    (void)hipMemsetAsync(counts, 0, (size_t)N * 4, stream);
    (void)hipMemsetAsync(bcounts, 0, (size_t)B * 4, stream);
    (void)hipMemsetAsync(stats, 0, 512, stream);

    // bucketed edge partition (shared by both layers)
    k_hist2<<<EB, 256, 0, stream>>>(col, counts, bcounts, E, B);
    k_dinv<<<(N + 255) / 256, 256, 0, stream>>>(counts, dinv, N);
    k_bscan<<<1, 256, 0, stream>>>(bcounts, boff, bcur, B, E);
    k_partition<<<EB, 256, 0, stream>>>(row, col, bcur, pairs, E, B);

    // layer 1
    k_gemm<FDIM, false><<<(N + 7) / 8, 256, 0, stream>>>(x, W1, dinv, B1, N,
                                                         nullptr, nullptr, nullptr, 0.f);
    k_agg<<<B, 256, 0, stream>>>(B1, dinv, boff, pairs, b1, B2, stats, N, B);

    // layer 2 (BN1+ReLU fused into gemm2's X load)
    k_gemm<HDIM, true><<<(N + 7) / 8, 256, 0, stream>>>(B2, W2, dinv, B1, N,
                                                        stats, g1, be1, invN);
    k_agg<<<B, 256, 0, stream>>>(B1, dinv, boff, pairs, b2, B2, stats + 2 * HDIM, N, B);
    k_bnapply<<<(N * HDIM + 255) / 256, 256, 0, stream>>>(B2, stats + 2 * HDIM, g2, be2,
                                                          (float*)d_out, N, invN);
}

// Round 5
// 743.864 us; speedup vs baseline: 3.9587x; 3.9587x over previous
//
#include <hip/hip_runtime.h>

#define FDIM 128
#define HDIM 32
#define BN_EPS 1e-5f
#define BK 64          // destination nodes per bucket
#define CHUNK 16384    // edges per partition/hist block
#define BMAX 4096      // max buckets supported (N <= 262144)

// ---------- per-bucket histogram (LDS) ----------
__global__ void k_hist2(const int* __restrict__ col, int* __restrict__ bcounts, int E, int B) {
    __shared__ int h[BMAX];
    for (int i = threadIdx.x; i < B; i += 256) h[i] = 0;
    __syncthreads();
    int base = blockIdx.x * CHUNK;
    int end = min(base + CHUNK, E);
    for (int e = base + threadIdx.x; e < end; e += 256)
        atomicAdd(&h[col[e] >> 6], 1);
    __syncthreads();
    for (int i = threadIdx.x; i < B; i += 256)
        if (h[i]) atomicAdd(&bcounts[i], h[i]);
}

// ---------- single-block exclusive scan of bucket counts ----------
__global__ void k_bscan(const int* __restrict__ bcounts, int* __restrict__ boff,
                        int* __restrict__ bcur, int* __restrict__ noff, int B, int E, int N) {
    __shared__ int tsum[256];
    __shared__ int wtot[4];
    const int t = threadIdx.x;
    const int per = (B + 255) / 256;
    const int b0 = t * per;
    int s = 0;
    for (int k = 0; k < per; ++k) { int i = b0 + k; if (i < B) s += bcounts[i]; }
    tsum[t] = s;
    __syncthreads();
    int lane = t & 63, w = t >> 6;
    int v = tsum[t];
    int inc = v;
    for (int off = 1; off < 64; off <<= 1) {
        int u = __shfl_up(inc, off);
        if (lane >= off) inc += u;
    }
    if (lane == 63) wtot[w] = inc;
    __syncthreads();
    int pre = 0;
    for (int k = 0; k < w; ++k) pre += wtot[k];
    int acc = pre + inc - v;  // exclusive prefix
    for (int k = 0; k < per; ++k) {
        int i = b0 + k;
        if (i < B) { boff[i] = acc; bcur[i] = acc; acc += bcounts[i]; }
    }
    if (t == 0) { boff[B] = E; noff[N] = E; }
}

// ---------- partition: pairs[] grouped by dst bucket, packed (src<<6 | dst&63) ----------
__global__ void k_partition(const int* __restrict__ row, const int* __restrict__ col,
                            int* __restrict__ bcur, unsigned* __restrict__ pairs,
                            int E, int B) {
    __shared__ int h[BMAX];
    for (int i = threadIdx.x; i < B; i += 256) h[i] = 0;
    __syncthreads();
    int base = blockIdx.x * CHUNK;
    int end = min(base + CHUNK, E);
    for (int e = base + threadIdx.x; e < end; e += 256)
        atomicAdd(&h[col[e] >> 6], 1);
    __syncthreads();
    for (int i = threadIdx.x; i < B; i += 256) {
        int c = h[i];
        if (c) h[i] = atomicAdd(&bcur[i], c);  // reserve contiguous range; h = running cursor
    }
    __syncthreads();
    for (int e = base + threadIdx.x; e < end; e += 256) {
        int c = col[e], r = row[e];
        int pos = atomicAdd(&h[c >> 6], 1);
        pairs[pos] = ((unsigned)r << 6) | (unsigned)(c & 63);
    }
}

// ---------- per-bucket counting sort -> exact CSR (srcs, noff) + dinv ----------
__global__ __launch_bounds__(256) void k_sort(const unsigned* __restrict__ pairs,
                                              const int* __restrict__ boff,
                                              int* __restrict__ srcs, int* __restrict__ noff,
                                              float* __restrict__ dinv, int N) {
    __shared__ int cnt[BK];
    __shared__ int cur[BK];
    const int bb = blockIdx.x;
    const int t = threadIdx.x;
    if (t < BK) cnt[t] = 0;
    __syncthreads();
    const int beg = boff[bb], end = boff[bb + 1];
    for (int i = beg + t; i < end; i += 256)
        atomicAdd(&cnt[pairs[i] & 63], 1);
    __syncthreads();
    if (t < 64) {  // wave 0: exclusive scan of 64 counts
        int v = cnt[t];
        int inc = v;
        for (int off = 1; off < 64; off <<= 1) {
            int u = __shfl_up(inc, off);
            if (t >= off) inc += u;
        }
        int start = beg + inc - v;
        cur[t] = start;
        int n = bb * BK + t;
        if (n < N) {
            noff[n] = start;
            dinv[n] = rsqrtf((float)(v + 1));  // +1 self-loop
        }
    }
    __syncthreads();
    for (int i = beg + t; i < end; i += 256) {
        unsigned p = pairs[i];
        int pos = atomicAdd(&cur[p & 63], 1);
        srcs[pos] = (int)(p >> 6);
    }
}

// ---------- GEMM: Y[n,32] = dinv[n] * (X[n,K] @ W[K,32]); optional fused BN+ReLU on X ----------
template <int K, bool APPLY_BN>
__global__ void k_gemm(const float* __restrict__ X, const float* __restrict__ W,
                       const float* __restrict__ dinv, float* __restrict__ Y, int n,
                       const float* __restrict__ stats, const float* __restrict__ gamma,
                       const float* __restrict__ beta, float invN) {
    __shared__ __align__(16) float Ws[K * HDIM];
    __shared__ __align__(16) float Xs[8 * K];
    __shared__ float bnsc[K], bnsh[K];
    const int tid = threadIdx.x;
    const int row0 = blockIdx.x * 8;

    if (APPLY_BN) {
        if (tid < K) {
            float mean = stats[tid] * invN;
            float var = stats[K + tid] * invN - mean * mean;
            float sc = gamma[tid] * rsqrtf(var + BN_EPS);
            bnsc[tid] = sc;
            bnsh[tid] = beta[tid] - mean * sc;
        }
        __syncthreads();
    }
    for (int i = tid * 4; i < K * HDIM; i += 1024) {
        *(float4*)&Ws[i] = *(const float4*)&W[i];
    }
    for (int i = tid * 4; i < 8 * K; i += 1024) {
        int r = i / K, k = i % K;
        int gr = row0 + r;
        float4 v = make_float4(0.f, 0.f, 0.f, 0.f);
        if (gr < n) v = *(const float4*)&X[(size_t)gr * K + k];
        if (APPLY_BN) {
            v.x = fmaxf(v.x * bnsc[k]     + bnsh[k],     0.f);
            v.y = fmaxf(v.y * bnsc[k + 1] + bnsh[k + 1], 0.f);
            v.z = fmaxf(v.z * bnsc[k + 2] + bnsh[k + 2], 0.f);
            v.w = fmaxf(v.w * bnsc[k + 3] + bnsh[k + 3], 0.f);
        }
        *(float4*)&Xs[i] = v;
    }
    __syncthreads();
    const int r = tid >> 5, c = tid & 31;
    const int grow = row0 + r;
    if (grow < n) {
        float acc = 0.f;
#pragma unroll
        for (int k = 0; k < K; ++k) acc += Xs[r * K + k] * Ws[k * HDIM + c];
        Y[(size_t)grow * HDIM + c] = dinv[grow] * acc;
    }
}

// ---------- gather-aggregate (register accumulate): agg[n] = dinv[n]*(hp[n]+sum hp[src])+b
// one wave per node (two halves split the edge list); fused BN-stats accumulation.
__global__ void k_aggregate(const float* __restrict__ hp, const float* __restrict__ dinv,
                            const int* __restrict__ offsets, const int* __restrict__ srcs,
                            const float* __restrict__ bias, float* __restrict__ agg,
                            float* __restrict__ stats, int N) {
    const int tid = threadIdx.x;
    const int lane = tid & 63;
    const int j = lane & 31;
    const int half = lane >> 5;
    const int wid = (blockIdx.x * blockDim.x + tid) >> 6;
    const int nw = (gridDim.x * blockDim.x) >> 6;
    const float bj = bias[j];
    float s = 0.f, s2 = 0.f;

    for (int n = wid; n < N; n += nw) {
        int beg = offsets[n], end = offsets[n + 1];
        float acc = half ? 0.f : hp[(size_t)n * HDIM + j];  // self-loop once
        int e = beg + half;
        for (; e + 6 < end; e += 8) {
            int r0 = srcs[e], r1 = srcs[e + 2], r2 = srcs[e + 4], r3 = srcs[e + 6];
            float v0 = hp[(size_t)r0 * HDIM + j], v1 = hp[(size_t)r1 * HDIM + j];
            float v2 = hp[(size_t)r2 * HDIM + j], v3 = hp[(size_t)r3 * HDIM + j];
            acc += (v0 + v1) + (v2 + v3);
        }
        for (; e < end; e += 2) acc += hp[(size_t)srcs[e] * HDIM + j];
        acc += __shfl_xor(acc, 32);          // combine halves; all 64 lanes hold total
        float out = dinv[n] * acc + bj;
        if (!half) agg[(size_t)n * HDIM + j] = out;
        s += out;                             // both halves accumulate -> halve at flush
        s2 += out * out;
    }

    __shared__ float ls[4][64], ls2[4][64];
    int w = tid >> 6;
    ls[w][lane] = s;
    ls2[w][lane] = s2;
    __syncthreads();
    if (tid < 32) {
        float t = 0.f;
#pragma unroll
        for (int k = 0; k < 4; ++k) t += ls[k][tid] + ls[k][tid + 32];
        atomicAdd(&stats[tid], 0.5f * t);
    } else if (tid < 64) {
        int jj = tid - 32;
        float t = 0.f;
#pragma unroll
        for (int k = 0; k < 4; ++k) t += ls2[k][jj] + ls2[k][jj + 32];
        atomicAdd(&stats[HDIM + jj], 0.5f * t);
    }
}

// ---------- final batchnorm apply (layer 2, no relu) ----------
__global__ void k_bnapply(const float* __restrict__ a, const float* __restrict__ stats,
                          const float* __restrict__ gamma, const float* __restrict__ beta,
                          float* __restrict__ out, int n, float invN) {
    int i = blockIdx.x * 256 + threadIdx.x;
    if (i < n * HDIM) {
        int j = i & 31;
        float mean = stats[j] * invN;
        float var = stats[HDIM + j] * invN - mean * mean;
        float g = gamma[j] * rsqrtf(var + BN_EPS);
        out[i] = (a[i] - mean) * g + beta[j];
    }
}

extern "C" void kernel_launch(void* const* d_in, const int* in_sizes, int n_in,
                              void* d_out, int out_size, void* d_ws, size_t ws_size,
                              hipStream_t stream) {
    const float* x   = (const float*)d_in[0];
    const int*   ei  = (const int*)d_in[1];
    const float* W1  = (const float*)d_in[2];
    const float* b1  = (const float*)d_in[3];
    const float* g1  = (const float*)d_in[4];
    const float* be1 = (const float*)d_in[5];
    const float* W2  = (const float*)d_in[6];
    const float* b2  = (const float*)d_in[7];
    const float* g2  = (const float*)d_in[8];
    const float* be2 = (const float*)d_in[9];

    const int N = in_sizes[0] / FDIM;
    const int E = in_sizes[1] / 2;
    const int* row = ei;      // source
    const int* col = ei + E;  // target
    const int B = (N + BK - 1) / BK;   // buckets (1563 for N=100k, fits BMAX)

    char* p = (char*)d_ws;
    auto alloc = [&](size_t bytes) { char* r = p; p += (bytes + 255) & ~(size_t)255; return r; };
    float*    dinv    = (float*)alloc((size_t)N * 4);
    int*      bcounts = (int*)alloc((size_t)B * 4);
    int*      boff    = (int*)alloc((size_t)(B + 1) * 4);
    int*      bcur    = (int*)alloc((size_t)B * 4);
    int*      noff    = (int*)alloc((size_t)(N + 1) * 4);
    unsigned* pairs   = (unsigned*)alloc((size_t)E * 4);
    int*      srcs    = (int*)alloc((size_t)E * 4);
    float*    B1      = (float*)alloc((size_t)N * HDIM * 4);
    float*    B2      = (float*)alloc((size_t)N * HDIM * 4);
    float*    stats   = (float*)alloc(512);  // layer1 [0,64), layer2 [64,128)

    const float invN = 1.0f / (float)N;
    const int EB = (E + CHUNK - 1) / CHUNK;

    (void)hipMemsetAsync(bcounts, 0, (size_t)B * 4, stream);
    (void)hipMemsetAsync(stats, 0, 512, stream);

    // bucketed edge partition + per-bucket counting sort -> exact CSR (shared by both layers)
    k_hist2<<<EB, 256, 0, stream>>>(col, bcounts, E, B);
    k_bscan<<<1, 256, 0, stream>>>(bcounts, boff, bcur, noff, B, E, N);
    k_partition<<<EB, 256, 0, stream>>>(row, col, bcur, pairs, E, B);
    k_sort<<<B, 256, 0, stream>>>(pairs, boff, srcs, noff, dinv, N);

    // layer 1
    k_gemm<FDIM, false><<<(N + 7) / 8, 256, 0, stream>>>(x, W1, dinv, B1, N,
                                                         nullptr, nullptr, nullptr, 0.f);
    k_aggregate<<<1280, 256, 0, stream>>>(B1, dinv, noff, srcs, b1, B2, stats, N);

    // layer 2 (BN1+ReLU fused into gemm2's X load)
    k_gemm<HDIM, true><<<(N + 7) / 8, 256, 0, stream>>>(B2, W2, dinv, B1, N,
                                                        stats, g1, be1, invN);
    k_aggregate<<<1280, 256, 0, stream>>>(B1, dinv, noff, srcs, b2, B2, stats + 2 * HDIM, N);
    k_bnapply<<<(N * HDIM + 255) / 256, 256, 0, stream>>>(B2, stats + 2 * HDIM, g2, be2,
                                                          (float*)d_out, N, invN);
}

// Round 6
// 666.416 us; speedup vs baseline: 4.4188x; 1.1162x over previous
//
#include <hip/hip_runtime.h>
#include <hip/hip_bf16.h>

#define FDIM 128
#define HDIM 32
#define BN_EPS 1e-5f
#define BK 64          // destination nodes per bucket
#define CHUNK 16384    // edges per partition/hist block
#define BMAX 4096      // max buckets supported (N <= 262144)

// ---------- per-bucket histogram (LDS) ----------
__global__ void k_hist2(const int* __restrict__ col, int* __restrict__ bcounts, int E, int B) {
    __shared__ int h[BMAX];
    for (int i = threadIdx.x; i < B; i += 256) h[i] = 0;
    __syncthreads();
    int base = blockIdx.x * CHUNK;
    int end = min(base + CHUNK, E);
    for (int e = base + threadIdx.x; e < end; e += 256)
        atomicAdd(&h[col[e] >> 6], 1);
    __syncthreads();
    for (int i = threadIdx.x; i < B; i += 256)
        if (h[i]) atomicAdd(&bcounts[i], h[i]);
}

// ---------- single-block exclusive scan of bucket counts ----------
__global__ void k_bscan(const int* __restrict__ bcounts, int* __restrict__ boff,
                        int* __restrict__ bcur, int* __restrict__ noff, int B, int E, int N) {
    __shared__ int tsum[256];
    __shared__ int wtot[4];
    const int t = threadIdx.x;
    const int per = (B + 255) / 256;
    const int b0 = t * per;
    int s = 0;
    for (int k = 0; k < per; ++k) { int i = b0 + k; if (i < B) s += bcounts[i]; }
    tsum[t] = s;
    __syncthreads();
    int lane = t & 63, w = t >> 6;
    int v = tsum[t];
    int inc = v;
    for (int off = 1; off < 64; off <<= 1) {
        int u = __shfl_up(inc, off);
        if (lane >= off) inc += u;
    }
    if (lane == 63) wtot[w] = inc;
    __syncthreads();
    int pre = 0;
    for (int k = 0; k < w; ++k) pre += wtot[k];
    int acc = pre + inc - v;  // exclusive prefix
    for (int k = 0; k < per; ++k) {
        int i = b0 + k;
        if (i < B) { boff[i] = acc; bcur[i] = acc; acc += bcounts[i]; }
    }
    if (t == 0) { boff[B] = E; noff[N] = E; }
}

// ---------- partition: pairs[] grouped by dst bucket, packed (src<<6 | dst&63) ----------
__global__ void k_partition(const int* __restrict__ row, const int* __restrict__ col,
                            int* __restrict__ bcur, unsigned* __restrict__ pairs,
                            int E, int B) {
    __shared__ int h[BMAX];
    for (int i = threadIdx.x; i < B; i += 256) h[i] = 0;
    __syncthreads();
    int base = blockIdx.x * CHUNK;
    int end = min(base + CHUNK, E);
    for (int e = base + threadIdx.x; e < end; e += 256)
        atomicAdd(&h[col[e] >> 6], 1);
    __syncthreads();
    for (int i = threadIdx.x; i < B; i += 256) {
        int c = h[i];
        if (c) h[i] = atomicAdd(&bcur[i], c);  // reserve contiguous range; h = running cursor
    }
    __syncthreads();
    for (int e = base + threadIdx.x; e < end; e += 256) {
        int c = col[e], r = row[e];
        int pos = atomicAdd(&h[c >> 6], 1);
        pairs[pos] = ((unsigned)r << 6) | (unsigned)(c & 63);
    }
}

// ---------- per-bucket counting sort -> exact CSR (srcs, noff) + dinv ----------
__global__ __launch_bounds__(256) void k_sort(const unsigned* __restrict__ pairs,
                                              const int* __restrict__ boff,
                                              int* __restrict__ srcs, int* __restrict__ noff,
                                              float* __restrict__ dinv, int N) {
    __shared__ int cnt[BK];
    __shared__ int cur[BK];
    const int bb = blockIdx.x;
    const int t = threadIdx.x;
    if (t < BK) cnt[t] = 0;
    __syncthreads();
    const int beg = boff[bb], end = boff[bb + 1];
    for (int i = beg + t; i < end; i += 256)
        atomicAdd(&cnt[pairs[i] & 63], 1);
    __syncthreads();
    if (t < 64) {  // wave 0: exclusive scan of 64 counts
        int v = cnt[t];
        int inc = v;
        for (int off = 1; off < 64; off <<= 1) {
            int u = __shfl_up(inc, off);
            if (t >= off) inc += u;
        }
        int start = beg + inc - v;
        cur[t] = start;
        int n = bb * BK + t;
        if (n < N) {
            noff[n] = start;
            dinv[n] = rsqrtf((float)(v + 1));  // +1 self-loop
        }
    }
    __syncthreads();
    for (int i = beg + t; i < end; i += 256) {
        unsigned p = pairs[i];
        int pos = atomicAdd(&cur[p & 63], 1);
        srcs[pos] = (int)(p >> 6);
    }
}

// ---------- GEMM: Y[n,32] = bf16(dinv[n]*(X[n,K]@W[K,32])); optional fused BN+ReLU on X ----------
template <int K, bool APPLY_BN>
__global__ void k_gemm(const float* __restrict__ X, const float* __restrict__ W,
                       const float* __restrict__ dinv, __hip_bfloat16* __restrict__ Y, int n,
                       const float* __restrict__ stats, const float* __restrict__ gamma,
                       const float* __restrict__ beta, float invN) {
    __shared__ __align__(16) float Ws[K * HDIM];
    __shared__ __align__(16) float Xs[8 * K];
    __shared__ float bnsc[K], bnsh[K];
    const int tid = threadIdx.x;
    const int row0 = blockIdx.x * 8;

    if (APPLY_BN) {
        if (tid < K) {
            float mean = stats[tid] * invN;
            float var = stats[K + tid] * invN - mean * mean;
            float sc = gamma[tid] * rsqrtf(var + BN_EPS);
            bnsc[tid] = sc;
            bnsh[tid] = beta[tid] - mean * sc;
        }
        __syncthreads();
    }
    for (int i = tid * 4; i < K * HDIM; i += 1024) {
        *(float4*)&Ws[i] = *(const float4*)&W[i];
    }
    for (int i = tid * 4; i < 8 * K; i += 1024) {
        int r = i / K, k = i % K;
        int gr = row0 + r;
        float4 v = make_float4(0.f, 0.f, 0.f, 0.f);
        if (gr < n) v = *(const float4*)&X[(size_t)gr * K + k];
        if (APPLY_BN) {
            v.x = fmaxf(v.x * bnsc[k]     + bnsh[k],     0.f);
            v.y = fmaxf(v.y * bnsc[k + 1] + bnsh[k + 1], 0.f);
            v.z = fmaxf(v.z * bnsc[k + 2] + bnsh[k + 2], 0.f);
            v.w = fmaxf(v.w * bnsc[k + 3] + bnsh[k + 3], 0.f);
        }
        *(float4*)&Xs[i] = v;
    }
    __syncthreads();
    const int r = tid >> 5, c = tid & 31;
    const int grow = row0 + r;
    if (grow < n) {
        float acc = 0.f;
#pragma unroll
        for (int k = 0; k < K; ++k) acc += Xs[r * K + k] * Ws[k * HDIM + c];
        Y[(size_t)grow * HDIM + c] = __float2bfloat16(dinv[grow] * acc);
    }
}

// ---------- gather-aggregate (register accumulate, bf16 gather):
// agg[n] = dinv[n]*(hp[n]+sum hp[src])+b ; fused BN-stats.
__global__ __launch_bounds__(256) void k_aggregate(const __hip_bfloat16* __restrict__ hp,
                                                   const float* __restrict__ dinv,
                                                   const int* __restrict__ offsets,
                                                   const int* __restrict__ srcs,
                                                   const float* __restrict__ bias,
                                                   float* __restrict__ agg,
                                                   float* __restrict__ stats, int N) {
    const int tid = threadIdx.x;
    const int lane = tid & 63;
    const int j = lane & 31;
    const int half = lane >> 5;
    const int wid = (blockIdx.x * 256 + tid) >> 6;
    const int nw = (gridDim.x * 256) >> 6;
    const float bj = bias[j];
    float s = 0.f, s2 = 0.f;

    for (int n = wid; n < N; n += nw) {
        int beg = offsets[n], end = offsets[n + 1];
        float acc = half ? 0.f : __bfloat162float(hp[(size_t)n * HDIM + j]);  // self-loop once
        int e = beg + half;
        for (; e + 14 < end; e += 16) {  // 8 outstanding gathers per half-wave
            int r0 = srcs[e],      r1 = srcs[e + 2],  r2 = srcs[e + 4],  r3 = srcs[e + 6];
            int r4 = srcs[e + 8],  r5 = srcs[e + 10], r6 = srcs[e + 12], r7 = srcs[e + 14];
            float v0 = __bfloat162float(hp[(size_t)r0 * HDIM + j]);
            float v1 = __bfloat162float(hp[(size_t)r1 * HDIM + j]);
            float v2 = __bfloat162float(hp[(size_t)r2 * HDIM + j]);
            float v3 = __bfloat162float(hp[(size_t)r3 * HDIM + j]);
            float v4 = __bfloat162float(hp[(size_t)r4 * HDIM + j]);
            float v5 = __bfloat162float(hp[(size_t)r5 * HDIM + j]);
            float v6 = __bfloat162float(hp[(size_t)r6 * HDIM + j]);
            float v7 = __bfloat162float(hp[(size_t)r7 * HDIM + j]);
            acc += ((v0 + v1) + (v2 + v3)) + ((v4 + v5) + (v6 + v7));
        }
        for (; e < end; e += 2) acc += __bfloat162float(hp[(size_t)srcs[e] * HDIM + j]);
        acc += __shfl_xor(acc, 32);          // combine halves; all 64 lanes hold total
        float out = dinv[n] * acc + bj;
        if (!half) agg[(size_t)n * HDIM + j] = out;
        s += out;                             // both halves accumulate -> halve at flush
        s2 += out * out;
    }

    __shared__ float ls[4][64], ls2[4][64];
    int w = tid >> 6;
    ls[w][lane] = s;
    ls2[w][lane] = s2;
    __syncthreads();
    if (tid < 32) {
        float t = 0.f;
#pragma unroll
        for (int k = 0; k < 4; ++k) t += ls[k][tid] + ls[k][tid + 32];
        atomicAdd(&stats[tid], 0.5f * t);
    } else if (tid < 64) {
        int jj = tid - 32;
        float t = 0.f;
#pragma unroll
        for (int k = 0; k < 4; ++k) t += ls2[k][jj] + ls2[k][jj + 32];
        atomicAdd(&stats[HDIM + jj], 0.5f * t);
    }
}

// ---------- final batchnorm apply (layer 2, no relu), float4 ----------
__global__ void k_bnapply(const float* __restrict__ a, const float* __restrict__ stats,
                          const float* __restrict__ gamma, const float* __restrict__ beta,
                          float* __restrict__ out, int n, float invN) {
    int i = (blockIdx.x * 256 + threadIdx.x) * 4;
    if (i < n * HDIM) {
        int j = i & 31;
        float4 v = *(const float4*)&a[i];
        float r[4];
        float* vp = &v.x;
#pragma unroll
        for (int k = 0; k < 4; ++k) {
            float mean = stats[j + k] * invN;
            float var = stats[HDIM + j + k] * invN - mean * mean;
            float g = gamma[j + k] * rsqrtf(var + BN_EPS);
            r[k] = (vp[k] - mean) * g + beta[j + k];
        }
        *(float4*)&out[i] = make_float4(r[0], r[1], r[2], r[3]);
    }
}

extern "C" void kernel_launch(void* const* d_in, const int* in_sizes, int n_in,
                              void* d_out, int out_size, void* d_ws, size_t ws_size,
                              hipStream_t stream) {
    const float* x   = (const float*)d_in[0];
    const int*   ei  = (const int*)d_in[1];
    const float* W1  = (const float*)d_in[2];
    const float* b1  = (const float*)d_in[3];
    const float* g1  = (const float*)d_in[4];
    const float* be1 = (const float*)d_in[5];
    const float* W2  = (const float*)d_in[6];
    const float* b2  = (const float*)d_in[7];
    const float* g2  = (const float*)d_in[8];
    const float* be2 = (const float*)d_in[9];

    const int N = in_sizes[0] / FDIM;
    const int E = in_sizes[1] / 2;
    const int* row = ei;      // source
    const int* col = ei + E;  // target
    const int B = (N + BK - 1) / BK;   // buckets (1563 for N=100k, fits BMAX)

    char* p = (char*)d_ws;
    auto alloc = [&](size_t bytes) { char* r = p; p += (bytes + 255) & ~(size_t)255; return r; };
    float*          dinv    = (float*)alloc((size_t)N * 4);
    int*            bcounts = (int*)alloc((size_t)B * 4);
    int*            boff    = (int*)alloc((size_t)(B + 1) * 4);
    int*            bcur    = (int*)alloc((size_t)B * 4);
    int*            noff    = (int*)alloc((size_t)(N + 1) * 4);
    unsigned*       pairs   = (unsigned*)alloc((size_t)E * 4);
    int*            srcs    = (int*)alloc((size_t)E * 4);
    __hip_bfloat16* B1      = (__hip_bfloat16*)alloc((size_t)N * HDIM * 2);  // hp (bf16)
    float*          B2      = (float*)alloc((size_t)N * HDIM * 4);           // agg (fp32)
    float*          stats   = (float*)alloc(512);  // layer1 [0,64), layer2 [64,128)

    const float invN = 1.0f / (float)N;
    const int EB = (E + CHUNK - 1) / CHUNK;

    (void)hipMemsetAsync(bcounts, 0, (size_t)B * 4, stream);
    (void)hipMemsetAsync(stats, 0, 512, stream);

    // bucketed edge partition + per-bucket counting sort -> exact CSR (shared by both layers)
    k_hist2<<<EB, 256, 0, stream>>>(col, bcounts, E, B);
    k_bscan<<<1, 256, 0, stream>>>(bcounts, boff, bcur, noff, B, E, N);
    k_partition<<<EB, 256, 0, stream>>>(row, col, bcur, pairs, E, B);
    k_sort<<<B, 256, 0, stream>>>(pairs, boff, srcs, noff, dinv, N);

    // layer 1
    k_gemm<FDIM, false><<<(N + 7) / 8, 256, 0, stream>>>(x, W1, dinv, B1, N,
                                                         nullptr, nullptr, nullptr, 0.f);
    k_aggregate<<<2048, 256, 0, stream>>>(B1, dinv, noff, srcs, b1, B2, stats, N);

    // layer 2 (BN1+ReLU fused into gemm2's X load)
    k_gemm<HDIM, true><<<(N + 7) / 8, 256, 0, stream>>>(B2, W2, dinv, B1, N,
                                                        stats, g1, be1, invN);
    k_aggregate<<<2048, 256, 0, stream>>>(B1, dinv, noff, srcs, b2, B2, stats + 2 * HDIM, N);
    k_bnapply<<<(N * HDIM / 4 + 255) / 256, 256, 0, stream>>>(B2, stats + 2 * HDIM, g2, be2,
                                                              (float*)d_out, N, invN);
}

// Round 7
// 637.364 us; speedup vs baseline: 4.6202x; 1.0456x over previous
//
#include <hip/hip_runtime.h>
#include <hip/hip_bf16.h>

#define FDIM 128
#define HDIM 32
#define BN_EPS 1e-5f
#define BK 256         // destination nodes per bucket
#define NBITS 8        // log2(BK)
#define CHUNK_H 4096   // edges per hist block
#define CHUNK_P 8192   // edges per partition block
#define BMAX 512       // max buckets (N <= 131072)

// ---------- per-bucket histogram (LDS) ----------
__global__ void k_hist2(const int* __restrict__ col, int* __restrict__ bcounts, int E, int B) {
    __shared__ int h[BMAX];
    for (int i = threadIdx.x; i < B; i += 256) h[i] = 0;
    __syncthreads();
    int base = blockIdx.x * CHUNK_H;
    int end = min(base + CHUNK_H, E);
    for (int e = base + threadIdx.x; e < end; e += 256)
        atomicAdd(&h[col[e] >> NBITS], 1);
    __syncthreads();
    for (int i = threadIdx.x; i < B; i += 256)
        if (h[i]) atomicAdd(&bcounts[i], h[i]);
}

// ---------- single-block exclusive scan of bucket counts ----------
__global__ void k_bscan(const int* __restrict__ bcounts, int* __restrict__ boff,
                        int* __restrict__ bcur, int* __restrict__ noff, int B, int E, int N) {
    __shared__ int tsum[256];
    __shared__ int wtot[4];
    const int t = threadIdx.x;
    const int per = (B + 255) / 256;
    const int b0 = t * per;
    int s = 0;
    for (int k = 0; k < per; ++k) { int i = b0 + k; if (i < B) s += bcounts[i]; }
    tsum[t] = s;
    __syncthreads();
    int lane = t & 63, w = t >> 6;
    int v = tsum[t];
    int inc = v;
    for (int off = 1; off < 64; off <<= 1) {
        int u = __shfl_up(inc, off);
        if (lane >= off) inc += u;
    }
    if (lane == 63) wtot[w] = inc;
    __syncthreads();
    int pre = 0;
    for (int k = 0; k < w; ++k) pre += wtot[k];
    int acc = pre + inc - v;  // exclusive prefix
    for (int k = 0; k < per; ++k) {
        int i = b0 + k;
        if (i < B) { boff[i] = acc; bcur[i] = acc; acc += bcounts[i]; }
    }
    if (t == 0) { boff[B] = E; noff[N] = E; }
}

// ---------- partition with LDS staging: pairs[] grouped by dst bucket, coalesced writes ----------
__global__ __launch_bounds__(256) void k_partition(const int* __restrict__ row,
                                                   const int* __restrict__ col,
                                                   int* __restrict__ bcur,
                                                   unsigned* __restrict__ pairs,
                                                   int E, int B) {
    __shared__ int h[BMAX];          // counts -> local cursors
    __shared__ int lbase[BMAX + 1];  // local exclusive scan
    __shared__ int delta[BMAX];      // global_base - local_base
    __shared__ unsigned pk[CHUNK_P]; // bucket-sorted packed pairs
    const int t = threadIdx.x;
    const int base = blockIdx.x * CHUNK_P;
    const int end = min(base + CHUNK_P, E);

    for (int i = t; i < B; i += 256) h[i] = 0;
    __syncthreads();
    // phase 1: local histogram
    for (int e = base + t; e < end; e += 256)
        atomicAdd(&h[col[e] >> NBITS], 1);
    __syncthreads();
    // phase 2: exclusive scan of h -> lbase (wave 0)
    if (t < 64) {
        int carry = 0;
        for (int bb = 0; bb < B; bb += 64) {
            int idx = bb + t;
            int v = (idx < B) ? h[idx] : 0;
            int inc = v;
            for (int off = 1; off < 64; off <<= 1) {
                int u = __shfl_up(inc, off);
                if (t >= off) inc += u;
            }
            if (idx < B) lbase[idx] = carry + inc - v;
            carry += __shfl(inc, 63);
        }
        if (t == 0) lbase[B] = carry;
    }
    __syncthreads();
    // phase 3: reserve global ranges
    for (int b = t; b < B; b += 256) {
        int c = h[b];
        if (c) {
            int g = atomicAdd(&bcur[b], c);
            delta[b] = g - lbase[b];
        }
    }
    __syncthreads();
    // phase 4: counting-sort into LDS (h becomes cursor)
    for (int b = t; b < B; b += 256) h[b] = lbase[b];
    __syncthreads();
    for (int e = base + t; e < end; e += 256) {
        int c = col[e], r = row[e];
        int lpos = atomicAdd(&h[c >> NBITS], 1);
        pk[lpos] = ((unsigned)r << NBITS) | (unsigned)(c & (BK - 1));
    }
    __syncthreads();
    // phase 5: coalesced write-out (binary search bucket for each position)
    const int tot = lbase[B];
    for (int i = t; i < tot; i += 256) {
        int lo = 0, hi = B - 1;
        while (lo < hi) {
            int mid = (lo + hi + 1) >> 1;
            if (lbase[mid] <= i) lo = mid; else hi = mid - 1;
        }
        pairs[delta[lo] + i] = pk[i];
    }
}

// ---------- per-bucket counting sort -> exact CSR (srcs, noff) + dinv ----------
__global__ __launch_bounds__(1024) void k_sort(const unsigned* __restrict__ pairs,
                                               const int* __restrict__ boff,
                                               int* __restrict__ srcs, int* __restrict__ noff,
                                               float* __restrict__ dinv, int N) {
    __shared__ int cnt[BK];
    __shared__ int cur[BK];
    const int bb = blockIdx.x;
    const int t = threadIdx.x;
    if (t < BK) cnt[t] = 0;
    __syncthreads();
    const int beg = boff[bb], end = boff[bb + 1];
    for (int i = beg + t; i < end; i += 1024)
        atomicAdd(&cnt[pairs[i] & (BK - 1)], 1);
    __syncthreads();
    if (t < 64) {  // wave 0: exclusive scan of BK counts
        int carry = 0;
        for (int base = 0; base < BK; base += 64) {
            int v = cnt[base + t];
            int inc = v;
            for (int off = 1; off < 64; off <<= 1) {
                int u = __shfl_up(inc, off);
                if (t >= off) inc += u;
            }
            cur[base + t] = beg + carry + inc - v;
            carry += __shfl(inc, 63);
        }
    }
    __syncthreads();
    if (t < BK) {
        int n = bb * BK + t;
        if (n < N) {
            noff[n] = cur[t];
            dinv[n] = rsqrtf((float)(cnt[t] + 1));  // +1 self-loop
        }
    }
    __syncthreads();
    for (int i = beg + t; i < end; i += 1024) {
        unsigned p = pairs[i];
        int pos = atomicAdd(&cur[p & (BK - 1)], 1);
        srcs[pos] = (int)(p >> NBITS);
    }
}

// ---------- GEMM: Y[n,32] = bf16(dinv[n]*(X[n,K]@W[K,32])); optional fused BN+ReLU on X ----------
template <int K, bool APPLY_BN>
__global__ void k_gemm(const float* __restrict__ X, const float* __restrict__ W,
                       const float* __restrict__ dinv, __hip_bfloat16* __restrict__ Y, int n,
                       const float* __restrict__ stats, const float* __restrict__ gamma,
                       const float* __restrict__ beta, float invN) {
    __shared__ __align__(16) float Ws[K * HDIM];
    __shared__ __align__(16) float Xs[8 * K];
    __shared__ float bnsc[K], bnsh[K];
    const int tid = threadIdx.x;
    const int row0 = blockIdx.x * 8;

    if (APPLY_BN) {
        if (tid < K) {
            float mean = stats[tid] * invN;
            float var = stats[K + tid] * invN - mean * mean;
            float sc = gamma[tid] * rsqrtf(var + BN_EPS);
            bnsc[tid] = sc;
            bnsh[tid] = beta[tid] - mean * sc;
        }
        __syncthreads();
    }
    for (int i = tid * 4; i < K * HDIM; i += 1024) {
        *(float4*)&Ws[i] = *(const float4*)&W[i];
    }
    for (int i = tid * 4; i < 8 * K; i += 1024) {
        int r = i / K, k = i % K;
        int gr = row0 + r;
        float4 v = make_float4(0.f, 0.f, 0.f, 0.f);
        if (gr < n) v = *(const float4*)&X[(size_t)gr * K + k];
        if (APPLY_BN) {
            v.x = fmaxf(v.x * bnsc[k]     + bnsh[k],     0.f);
            v.y = fmaxf(v.y * bnsc[k + 1] + bnsh[k + 1], 0.f);
            v.z = fmaxf(v.z * bnsc[k + 2] + bnsh[k + 2], 0.f);
            v.w = fmaxf(v.w * bnsc[k + 3] + bnsh[k + 3], 0.f);
        }
        *(float4*)&Xs[i] = v;
    }
    __syncthreads();
    const int r = tid >> 5, c = tid & 31;
    const int grow = row0 + r;
    if (grow < n) {
        float acc = 0.f;
#pragma unroll
        for (int k = 0; k < K; ++k) acc += Xs[r * K + k] * Ws[k * HDIM + c];
        Y[(size_t)grow * HDIM + c] = __float2bfloat16(dinv[grow] * acc);
    }
}

// ---------- gather-aggregate (register accumulate, bf16 gather):
// agg[n] = dinv[n]*(hp[n]+sum hp[src])+b ; fused BN-stats.
__global__ __launch_bounds__(256) void k_aggregate(const __hip_bfloat16* __restrict__ hp,
                                                   const float* __restrict__ dinv,
                                                   const int* __restrict__ offsets,
                                                   const int* __restrict__ srcs,
                                                   const float* __restrict__ bias,
                                                   float* __restrict__ agg,
                                                   float* __restrict__ stats, int N) {
    const int tid = threadIdx.x;
    const int lane = tid & 63;
    const int j = lane & 31;
    const int half = lane >> 5;
    const int wid = (blockIdx.x * 256 + tid) >> 6;
    const int nw = (gridDim.x * 256) >> 6;
    const float bj = bias[j];
    float s = 0.f, s2 = 0.f;

    for (int n = wid; n < N; n += nw) {
        int beg = offsets[n], end = offsets[n + 1];
        float acc = half ? 0.f : __bfloat162float(hp[(size_t)n * HDIM + j]);  // self-loop once
        int e = beg + half;
        for (; e + 30 < end; e += 32) {  // 16 outstanding gathers per half-wave
            int rr[16];
            float vv[16];
#pragma unroll
            for (int k = 0; k < 16; ++k) rr[k] = srcs[e + 2 * k];
#pragma unroll
            for (int k = 0; k < 16; ++k) vv[k] = __bfloat162float(hp[(size_t)rr[k] * HDIM + j]);
#pragma unroll
            for (int k = 0; k < 16; ++k) acc += vv[k];
        }
        for (; e + 6 < end; e += 8) {
            int r0 = srcs[e], r1 = srcs[e + 2], r2 = srcs[e + 4], r3 = srcs[e + 6];
            float v0 = __bfloat162float(hp[(size_t)r0 * HDIM + j]);
            float v1 = __bfloat162float(hp[(size_t)r1 * HDIM + j]);
            float v2 = __bfloat162float(hp[(size_t)r2 * HDIM + j]);
            float v3 = __bfloat162float(hp[(size_t)r3 * HDIM + j]);
            acc += (v0 + v1) + (v2 + v3);
        }
        for (; e < end; e += 2) acc += __bfloat162float(hp[(size_t)srcs[e] * HDIM + j]);
        acc += __shfl_xor(acc, 32);          // combine halves; all 64 lanes hold total
        float out = dinv[n] * acc + bj;
        if (!half) agg[(size_t)n * HDIM + j] = out;
        s += out;                             // both halves accumulate -> halve at flush
        s2 += out * out;
    }

    __shared__ float ls[4][64], ls2[4][64];
    int w = tid >> 6;
    ls[w][lane] = s;
    ls2[w][lane] = s2;
    __syncthreads();
    if (tid < 32) {
        float t = 0.f;
#pragma unroll
        for (int k = 0; k < 4; ++k) t += ls[k][tid] + ls[k][tid + 32];
        atomicAdd(&stats[tid], 0.5f * t);
    } else if (tid < 64) {
        int jj = tid - 32;
        float t = 0.f;
#pragma unroll
        for (int k = 0; k < 4; ++k) t += ls2[k][jj] + ls2[k][jj + 32];
        atomicAdd(&stats[HDIM + jj], 0.5f * t);
    }
}

// ---------- final batchnorm apply (layer 2, no relu), float4 ----------
__global__ void k_bnapply(const float* __restrict__ a, const float* __restrict__ stats,
                          const float* __restrict__ gamma, const float* __restrict__ beta,
                          float* __restrict__ out, int n, float invN) {
    int i = (blockIdx.x * 256 + threadIdx.x) * 4;
    if (i < n * HDIM) {
        int j = i & 31;
        float4 v = *(const float4*)&a[i];
        float r[4];
        float* vp = &v.x;
#pragma unroll
        for (int k = 0; k < 4; ++k) {
            float mean = stats[j + k] * invN;
            float var = stats[HDIM + j + k] * invN - mean * mean;
            float g = gamma[j + k] * rsqrtf(var + BN_EPS);
            r[k] = (vp[k] - mean) * g + beta[j + k];
        }
        *(float4*)&out[i] = make_float4(r[0], r[1], r[2], r[3]);
    }
}

extern "C" void kernel_launch(void* const* d_in, const int* in_sizes, int n_in,
                              void* d_out, int out_size, void* d_ws, size_t ws_size,
                              hipStream_t stream) {
    const float* x   = (const float*)d_in[0];
    const int*   ei  = (const int*)d_in[1];
    const float* W1  = (const float*)d_in[2];
    const float* b1  = (const float*)d_in[3];
    const float* g1  = (const float*)d_in[4];
    const float* be1 = (const float*)d_in[5];
    const float* W2  = (const float*)d_in[6];
    const float* b2  = (const float*)d_in[7];
    const float* g2  = (const float*)d_in[8];
    const float* be2 = (const float*)d_in[9];

    const int N = in_sizes[0] / FDIM;
    const int E = in_sizes[1] / 2;
    const int* row = ei;      // source
    const int* col = ei + E;  // target
    const int B = (N + BK - 1) / BK;   // buckets (391 for N=100k, fits BMAX)

    char* p = (char*)d_ws;
    auto alloc = [&](size_t bytes) { char* r = p; p += (bytes + 255) & ~(size_t)255; return r; };
    float*          dinv    = (float*)alloc((size_t)N * 4);
    int*            bcounts = (int*)alloc((size_t)B * 4);
    int*            boff    = (int*)alloc((size_t)(B + 1) * 4);
    int*            bcur    = (int*)alloc((size_t)B * 4);
    int*            noff    = (int*)alloc((size_t)(N + 1) * 4);
    unsigned*       pairs   = (unsigned*)alloc((size_t)E * 4);
    int*            srcs    = (int*)alloc((size_t)E * 4);
    __hip_bfloat16* B1      = (__hip_bfloat16*)alloc((size_t)N * HDIM * 2);  // hp (bf16)
    float*          B2      = (float*)alloc((size_t)N * HDIM * 4);           // agg (fp32)
    float*          stats   = (float*)alloc(512);  // layer1 [0,64), layer2 [64,128)

    const float invN = 1.0f / (float)N;
    const int EBH = (E + CHUNK_H - 1) / CHUNK_H;
    const int EBP = (E + CHUNK_P - 1) / CHUNK_P;

    (void)hipMemsetAsync(bcounts, 0, (size_t)B * 4, stream);
    (void)hipMemsetAsync(stats, 0, 512, stream);

    // bucketed edge partition + per-bucket counting sort -> exact CSR (shared by both layers)
    k_hist2<<<EBH, 256, 0, stream>>>(col, bcounts, E, B);
    k_bscan<<<1, 256, 0, stream>>>(bcounts, boff, bcur, noff, B, E, N);
    k_partition<<<EBP, 256, 0, stream>>>(row, col, bcur, pairs, E, B);
    k_sort<<<B, 1024, 0, stream>>>(pairs, boff, srcs, noff, dinv, N);

    // layer 1
    k_gemm<FDIM, false><<<(N + 7) / 8, 256, 0, stream>>>(x, W1, dinv, B1, N,
                                                         nullptr, nullptr, nullptr, 0.f);
    k_aggregate<<<2048, 256, 0, stream>>>(B1, dinv, noff, srcs, b1, B2, stats, N);

    // layer 2 (BN1+ReLU fused into gemm2's X load)
    k_gemm<HDIM, true><<<(N + 7) / 8, 256, 0, stream>>>(B2, W2, dinv, B1, N,
                                                        stats, g1, be1, invN);
    k_aggregate<<<2048, 256, 0, stream>>>(B1, dinv, noff, srcs, b2, B2, stats + 2 * HDIM, N);
    k_bnapply<<<(N * HDIM / 4 + 255) / 256, 256, 0, stream>>>(B2, stats + 2 * HDIM, g2, be2,
                                                              (float*)d_out, N, invN);
}